// Round 7
// baseline (19669.011 us; speedup 1.0000x reference)
//
#include <hip/hip_runtime.h>

// ---------------------------------------------------------------------------
// TacotronMelDecoder on MI355X (gfx950) — precision-hardened persistent scan.
// R7 (= R6 fixed): cross-block state reads (hp/uctx/qbuf/sums) use PLAIN
// CACHED loads + agent-scope ACQUIRE fence (__builtin_amdgcn_fence ->
// buffer_inv) after each global barrier, replacing R5's MALL-direct atomic
// loads (~50MB/step uncached, concurrency-limited ~55us/step). Writers stay
// agent-scope write-through. Numerics identical to R3-R5 (absmax ~0.12).
// ---------------------------------------------------------------------------

typedef unsigned short us16;
typedef unsigned int u32;
typedef unsigned long long u64;
typedef __attribute__((ext_vector_type(8))) short bf16x8;
typedef __attribute__((ext_vector_type(4))) float f32x4;

#define MFMA16 __builtin_amdgcn_mfma_f32_16x16x32_bf16
#define AGT __HIP_MEMORY_SCOPE_AGENT

__device__ __forceinline__ us16 f2bf(float f){
  u32 u = __builtin_bit_cast(u32, f);
  u += 0x7fffu + ((u >> 16) & 1u);
  return (us16)(u >> 16);
}
__device__ __forceinline__ float bf2f(us16 h){
  return __builtin_bit_cast(float, ((u32)h) << 16);
}
__device__ __forceinline__ float h2f(us16 u){
  _Float16 h = __builtin_bit_cast(_Float16, u); return (float)h;
}
__device__ __forceinline__ us16 f2h(float f){
  _Float16 h = (_Float16)f; return __builtin_bit_cast(us16, h);
}
__device__ __forceinline__ void split3(float v, us16& s0, us16& s1, us16& s2){
  s0 = f2bf(v); float r = v - bf2f(s0);
  s1 = f2bf(r); r -= bf2f(s1);
  s2 = f2bf(r);
}
__device__ __forceinline__ float tanh_fast(float x){
  float e = __expf(-2.f * fmaxf(x, -40.f));
  return (1.f - e) / (1.f + e);
}

__device__ __forceinline__ u32 aload32(const u32* p){
  return __hip_atomic_load(p, __ATOMIC_RELAXED, AGT);
}
__device__ __forceinline__ void astore16(us16* p, us16 v){
  __hip_atomic_store(p, v, __ATOMIC_RELAXED, AGT);
}
__device__ __forceinline__ void astoref(float* p, float v){
  __hip_atomic_store(p, v, __ATOMIC_RELAXED, AGT);
}
__device__ __forceinline__ void aaddf(float* p, float v){
  __hip_atomic_fetch_add(p, v, __ATOMIC_RELAXED, AGT);
}
// plain cached 16B load (coherence via post-barrier acquire fence)
__device__ __forceinline__ bf16x8 ld16(const us16* p){
  return *(const bf16x8*)p;
}
// opacity: force a loaded fragment to stay in VGPRs (non-rematerializable)
__device__ __forceinline__ bf16x8 pin_reg(bf16x8 v){
  f32x4 t = __builtin_bit_cast(f32x4, v);
  asm volatile("" : "+v"(t));
  return __builtin_bit_cast(bf16x8, t);
}
// ctx fragment: 8 fp32 partial sums (cached) -> *rs -> triple-split bf16 frags
__device__ __forceinline__ void ctx_frag3(const float* p, float rs,
                                          bf16x8& f0, bf16x8& f1, bf16x8& f2){
  float4 t0 = *(const float4*)p;
  float4 t1 = *(const float4*)(p + 4);
  float tf[8] = {t0.x, t0.y, t0.z, t0.w, t1.x, t1.y, t1.z, t1.w};
#pragma unroll
  for (int i = 0; i < 8; ++i){
    float v = tf[i] * rs;
    us16 s0, s1, s2; split3(v, s0, s1, s2);
    f0[i] = (short)s0; f1[i] = (short)s1; f2[i] = (short)s2;
  }
}

// ---------------- workspace layout (bytes) ----------------
#define OFF_WTA   0ull            // 3 planes [4096][2048] bf16 (cols permuted u*4+gate)
#define OFF_WQT   50331648ull     // 3 planes [1024][1024] bf16 (Wq^T)
#define OFF_X2P   56623104ull     // 3 planes [32*200][512] bf16 (prenet out)
#define OFF_KEYH  76283904ull     // [8192][1024] fp16 hi
#define OFF_KEYL  93061120ull     // [8192][1024] fp16 lo
#define OFF_X1    76283904ull     // alias: [6400][1024] f32 (dead before keys written)
#define OFF_HIST  109838336ull    // [201][32][1536] bf16 state history (epilogue only)
#define OFF_HP    129597440ull    // [2][3][32][1024] bf16 h planes
#define OFF_QBUF  130187264ull    // [32][1024] f32
#define OFF_UCTX  130318336ull    // [2][32][512] f32 (atomic ctx accum)
#define OFF_SUMS  130449408ull    // [2][32] f32 (atomic softmax sums)
#define OFF_CBUF  130449664ull    // [32][1024] f32
#define OFF_HF32  130580736ull    // [32][1024] f32
#define OFF_WAPN  130711808ull    // [1536][80] bf16 (Wa@Wp natural)
#define OFF_BPERM 130957568ull    // [4096] f32
#define OFF_BAR   130973952ull
#define TOTAL_WS  130974976ull

#define WTPL 8388608ull
#define WQPL 1048576ull
#define X2PL 3276800ull

// ---------------- init ----------------
__global__ void k_zero_init(u32* hp, u32* uctx, u32* cbuf, float* sums, u32* bar){
  u32 id = blockIdx.x * 256u + threadIdx.x;
  const u32 gs = 65536u;
  for (u32 i = id; i < 98304u; i += gs) hp[i]   = 0;
  for (u32 i = id; i < 32768u; i += gs) uctx[i] = 0;
  for (u32 i = id; i < 32768u; i += gs) cbuf[i] = 0;
  for (u32 i = id; i < 256u;   i += gs) bar[i]  = 0;
  if (id < 64u) sums[id] = (id < 32u) ? 0.f : 1.f;   // sums[1]=1: t=0 ctx = 0/1
}

__global__ void k_bperm(const float* __restrict__ bl, float* __restrict__ bpm){
  int c = blockIdx.x * 256 + threadIdx.x;
  if (c < 4096) bpm[((c & 1023) << 2) | (c >> 10)] = bl[c];
}

// ---------------- transpose f32 -> 3 bf16 planes (+optional gate perm) ----------------
__global__ void k_transp3(const float* __restrict__ src, us16* __restrict__ dst,
                          int srows, int scols, int ldd, long long pstride, int perm){
  __shared__ float tile[32][33];
  int bx = blockIdx.x * 32, by = blockIdx.y * 32;
  int tx = threadIdx.x & 31, ty = threadIdx.x >> 5;
#pragma unroll
  for (int i = 0; i < 4; ++i){
    int r = by + ty + i * 8, c = bx + tx;
    tile[ty + i * 8][tx] = (r < srows && c < scols) ? src[(size_t)r * scols + c] : 0.f;
  }
  __syncthreads();
#pragma unroll
  for (int i = 0; i < 4; ++i){
    int c = bx + ty + i * 8;   // src col -> dst row
    int r = by + tx;           // src row -> dst col
    if (c < scols && r < srows){
      int oc = perm ? (((c & 1023) << 2) | (c >> 10)) : c;
      float v = tile[tx][ty + i * 8];
      us16 s0, s1, s2; split3(v, s0, s1, s2);
      size_t base = (size_t)oc * ldd + r;
      dst[base] = s0; dst[(size_t)pstride + base] = s1; dst[2ull * pstride + base] = s2;
    }
  }
}

// ---------------- generic triple-split GEMM: C[M,N] = A[M,K] @ B[K,N] ----------------
// modes: 0 f32+bias+relu | 1 relu -> x2 triple planes | 2 keys fp16 pair
//        3 fold -> WT_A triple planes (+Wh, gate perm) | 4 bf16 plain
//        5 mel f32 (+bias, row remap) | 6 f32 plain
template<int NP, int AF, int BF>
__global__ void __launch_bounds__(256)
k_gemm3(const void* __restrict__ Ap, const void* __restrict__ Bp, void* __restrict__ outp,
        int M, int N, int K, int mode, const float* __restrict__ aux, int ldd){
  __shared__ us16 At[NP][128][72];
  __shared__ us16 Bt[NP][64][72];
  const int tid = threadIdx.x, wv = tid >> 6, lane = tid & 63;
  const int r0 = lane & 15, kg = lane >> 4;
  const int rb = blockIdx.x * 128, cb = blockIdx.y * 64;
  f32x4 acc[2][4];
#pragma unroll
  for (int a = 0; a < 2; ++a)
#pragma unroll
    for (int b = 0; b < 4; ++b) acc[a][b] = (f32x4){0.f, 0.f, 0.f, 0.f};

  const int nkt = (K + 63) >> 6;
  for (int kt = 0; kt < nkt; ++kt){
    const int kb = kt * 64;
    for (int e = tid; e < 8192; e += 256){
      int r = e >> 6, k = e & 63, ga = rb + r, gk = kb + k;
      bool ok = (ga < M) && (gk < K);
      if constexpr (AF){
        float v = ok ? ((const float*)Ap)[(size_t)ga * K + gk] : 0.f;
        us16 s0, s1, s2; split3(v, s0, s1, s2);
        At[0][r][k] = s0;
        if constexpr (NP == 3){ At[1][r][k] = s1; At[2][r][k] = s2; }
      } else {
        At[0][r][k] = ok ? ((const us16*)Ap)[(size_t)ga * K + gk] : (us16)0;
      }
    }
    for (int e = tid; e < 4096; e += 256){
      int kr = e >> 6, c = e & 63, gk = kb + kr, gc = cb + c;
      bool ok = (gk < K) && (gc < N);
      if constexpr (BF){
        float v = ok ? ((const float*)Bp)[(size_t)gk * N + gc] : 0.f;
        us16 s0, s1, s2; split3(v, s0, s1, s2);
        Bt[0][c][kr] = s0;
        if constexpr (NP == 3){ Bt[1][c][kr] = s1; Bt[2][c][kr] = s2; }
      } else {
        Bt[0][c][kr] = ok ? ((const us16*)Bp)[(size_t)gk * N + gc] : (us16)0;
      }
    }
    __syncthreads();
#pragma unroll
    for (int kk = 0; kk < 64; kk += 32){
      bf16x8 af[NP][2];
#pragma unroll
      for (int p = 0; p < NP; ++p){
        af[p][0] = *(const bf16x8*)&At[p][wv * 32 + r0][kk + kg * 8];
        af[p][1] = *(const bf16x8*)&At[p][wv * 32 + 16 + r0][kk + kg * 8];
      }
#pragma unroll
      for (int cf = 0; cf < 4; ++cf){
        bf16x8 bv[NP];
#pragma unroll
        for (int p = 0; p < NP; ++p) bv[p] = *(const bf16x8*)&Bt[p][cf * 16 + r0][kk + kg * 8];
#pragma unroll
        for (int rf = 0; rf < 2; ++rf){
          acc[rf][cf] = MFMA16(af[0][rf], bv[0], acc[rf][cf], 0, 0, 0);
          if constexpr (NP == 3){
            acc[rf][cf] = MFMA16(af[0][rf], bv[1], acc[rf][cf], 0, 0, 0);
            acc[rf][cf] = MFMA16(af[1][rf], bv[0], acc[rf][cf], 0, 0, 0);
            acc[rf][cf] = MFMA16(af[0][rf], bv[2], acc[rf][cf], 0, 0, 0);
            acc[rf][cf] = MFMA16(af[1][rf], bv[1], acc[rf][cf], 0, 0, 0);
            acc[rf][cf] = MFMA16(af[2][rf], bv[0], acc[rf][cf], 0, 0, 0);
          }
        }
      }
    }
    __syncthreads();
  }
  us16* o16 = (us16*)outp; float* of = (float*)outp;
#pragma unroll
  for (int rf = 0; rf < 2; ++rf)
#pragma unroll
    for (int cf = 0; cf < 4; ++cf)
#pragma unroll
      for (int i = 0; i < 4; ++i){
        int r = rb + wv * 32 + rf * 16 + kg * 4 + i;
        int c = cb + cf * 16 + r0;
        if (r >= M || c >= N) continue;
        float v = acc[rf][cf][i];
        if (mode == 0){
          of[(size_t)r * ldd + c] = fmaxf(v + aux[c], 0.f);
        } else if (mode == 1){
          v = fmaxf(v + aux[c], 0.f);
          us16 s0, s1, s2; split3(v, s0, s1, s2);
          size_t b2 = (size_t)r * ldd + c;
          o16[b2] = s0; o16[X2PL + b2] = s1; o16[2 * X2PL + b2] = s2;
        } else if (mode == 2){
          us16 hh = f2h(v); float rem = v - h2f(hh); us16 hl = f2h(rem);
          size_t b2 = (size_t)r * 1024 + c;
          o16[b2] = hh; o16[WTPL + b2] = hl;
        } else if (mode == 3){
          float w = v + (r < 1024 ? aux[(size_t)r * 4096 + c] : 0.f);
          int pc = (c & 1023) * 4 + (c >> 10);
          us16 s0, s1, s2; split3(w, s0, s1, s2);
          size_t b2 = (size_t)pc * 2048 + 512 + r;
          o16[b2] = s0; o16[WTPL + b2] = s1; o16[2 * WTPL + b2] = s2;
        } else if (mode == 4){
          o16[(size_t)r * ldd + c] = f2bf(v);
        } else if (mode == 5){
          of[((size_t)(r & 31) * 200 + (r >> 5)) * 80 + c] = v + aux[c];
        } else {
          of[(size_t)r * ldd + c] = v;
        }
      }
}

// ---------------- global barrier + agent acquire fence ----------------
// Writers use agent-scope write-through stores; the pre-barrier vmcnt(0)
// drains them. After the release, the acquire fence (buffer_inv) invalidates
// stale L1/L2 lines so subsequent PLAIN loads refetch from MALL once per XCD
// and then hit L2 for the other 31 blocks on the XCD.
__device__ __forceinline__ void gbar(u32* bar, u32 ep, int tid, int blk){
  __syncthreads();
  if (tid == 0){
    asm volatile("s_waitcnt vmcnt(0)" ::: "memory");
    u32 g = (u32)(blk >> 5);
    u32 old = __hip_atomic_fetch_add(&bar[g * 32], 1u, __ATOMIC_RELAXED, AGT);
    if (old == 32u * ep - 1u){
      u32 r = __hip_atomic_fetch_add(&bar[248], 1u, __ATOMIC_RELAXED, AGT);
      if (r == 8u * ep - 1u)
        __hip_atomic_store(&bar[252], ep, __ATOMIC_RELAXED, AGT);
    }
    while (aload32(&bar[252]) < ep) __builtin_amdgcn_s_sleep(1);
    __builtin_amdgcn_sched_barrier(0);
  }
  __syncthreads();
  __builtin_amdgcn_fence(__ATOMIC_ACQUIRE, "agent");
}

// ---------------- persistent scan kernel ----------------
struct CoopA {
  const us16 *wta, *wqt, *x2p, *kh, *kl;
  const float *mem, *vatt, *bperm;
  us16 *hist, *hp;
  float *qbuf, *uctx, *sums, *cbuf, *hf32;
  u32 *bar;
};

__global__ void __launch_bounds__(512, 2) k_coop(CoopA a){
  __shared__ us16 khi[32][1024];
  __shared__ us16 klo[32][1024];
  __shared__ float zp[8][512];
  __shared__ float esc[32];
  __shared__ float rs_lds[32];

  const int tid = threadIdx.x, blk = blockIdx.x;
  const int wv = tid >> 6, lane = tid & 63;
  const int r0 = lane & 15, kg = lane >> 4;
  const int cb_b = blk >> 3, cb_s0 = (blk & 7) * 32;   // phase-C identity
  const int colbase = blk * 16;
  const int u0 = lane * 16;

  // WTA slice pinned in registers for all 200 steps (96 VGPRs/thread).
  bf16x8 wr[8][3];
#pragma unroll
  for (int ks = 0; ks < 8; ++ks){
    const size_t wb = (size_t)(colbase + r0) * 2048 + (size_t)wv * 256 + ks * 32 + kg * 8;
#pragma unroll
    for (int p = 0; p < 3; ++p)
      wr[ks][p] = pin_reg(*(const bf16x8*)&a.wta[(size_t)p * WTPL + wb]);
  }
  // WQT slice pinned for q-blocks (48 VGPRs on blocks 0..63)
  bf16x8 wq[4][3];
  if (blk < 64){
#pragma unroll
    for (int ks = 0; ks < 4; ++ks){
      const size_t wb = (size_t)(colbase + r0) * 1024 + (size_t)wv * 128 + ks * 32 + kg * 8;
#pragma unroll
      for (int p = 0; p < 3; ++p)
        wq[ks][p] = pin_reg(*(const bf16x8*)&a.wqt[(size_t)p * WQPL + wb]);
    }
  }

  // keys slice resident in LDS for all 200 steps
  {
    const size_t kbase = ((size_t)(cb_b * 256 + cb_s0)) * 1024;
    for (int i = tid; i < 4096; i += 512){
      int r = i >> 7, c8 = (i & 127) * 8;
      *(bf16x8*)&khi[r][c8] = *(const bf16x8*)&a.kh[kbase + (size_t)r * 1024 + c8];
      *(bf16x8*)&klo[r][c8] = *(const bf16x8*)&a.kl[kbase + (size_t)r * 1024 + c8];
    }
  }
  __syncthreads();

  u32 ep = 0;
  for (int t = 0; t < 200; ++t){
    const int par = t & 1, p1 = (t - 1) & 1;
    // ===== phase A: ctx finalize inline; z = [x|h|ctx] @ WT_A (regs); gates =====
    {
      if (tid < 32) rs_lds[tid] = 1.f / a.sums[p1 * 32 + tid];
      __syncthreads();
      // side task: write hist[t] ctx part (state after step t-1) for epilogue
      if (tid < 64){
        int flat = blk * 64 + tid;          // 0..16383 = b*512+e
        int b = flat >> 9, e = flat & 511;
        float v = a.uctx[p1 * 16384 + flat];
        a.hist[(size_t)(t * 32 + b) * 1536 + 1024 + e] = f2bf(v * rs_lds[b]);
      }
      f32x4 acc0 = (f32x4){0.f,0.f,0.f,0.f}, acc1 = acc0;
#pragma unroll
      for (int ks = 0; ks < 8; ++ks){
        const int k0 = wv * 256 + ks * 32;
        const int kf = k0 + kg * 8;
        bf16x8 w0 = wr[ks][0], w1 = wr[ks][1], w2 = wr[ks][2];
        bf16x8 a00, a01, a02, a10, a11, a12;
        if (wv < 2){
          const size_t xb0 = ((size_t)r0 * 200 + t) * 512 + kf;
          const size_t xb1 = ((size_t)(r0 + 16) * 200 + t) * 512 + kf;
          a00 = *(const bf16x8*)&a.x2p[xb0];
          a01 = *(const bf16x8*)&a.x2p[X2PL + xb0];
          a02 = *(const bf16x8*)&a.x2p[2 * X2PL + xb0];
          a10 = *(const bf16x8*)&a.x2p[xb1];
          a11 = *(const bf16x8*)&a.x2p[X2PL + xb1];
          a12 = *(const bf16x8*)&a.x2p[2 * X2PL + xb1];
        } else if (wv < 6){
          const int hk = kf - 512;
          a00 = ld16(&a.hp[((size_t)(p1 * 3 + 0) * 32 + r0) * 1024 + hk]);
          a01 = ld16(&a.hp[((size_t)(p1 * 3 + 1) * 32 + r0) * 1024 + hk]);
          a02 = ld16(&a.hp[((size_t)(p1 * 3 + 2) * 32 + r0) * 1024 + hk]);
          a10 = ld16(&a.hp[((size_t)(p1 * 3 + 0) * 32 + r0 + 16) * 1024 + hk]);
          a11 = ld16(&a.hp[((size_t)(p1 * 3 + 1) * 32 + r0 + 16) * 1024 + hk]);
          a12 = ld16(&a.hp[((size_t)(p1 * 3 + 2) * 32 + r0 + 16) * 1024 + hk]);
        } else {
          const int ek = kf - 1536;
          ctx_frag3(a.uctx + p1 * 16384 + r0 * 512 + ek,        rs_lds[r0],      a00, a01, a02);
          ctx_frag3(a.uctx + p1 * 16384 + (r0 + 16) * 512 + ek, rs_lds[r0 + 16], a10, a11, a12);
        }
        acc0 = MFMA16(a00, w0, acc0, 0,0,0); acc0 = MFMA16(a00, w1, acc0, 0,0,0);
        acc0 = MFMA16(a01, w0, acc0, 0,0,0); acc0 = MFMA16(a00, w2, acc0, 0,0,0);
        acc0 = MFMA16(a01, w1, acc0, 0,0,0); acc0 = MFMA16(a02, w0, acc0, 0,0,0);
        acc1 = MFMA16(a10, w0, acc1, 0,0,0); acc1 = MFMA16(a10, w1, acc1, 0,0,0);
        acc1 = MFMA16(a11, w0, acc1, 0,0,0); acc1 = MFMA16(a10, w2, acc1, 0,0,0);
        acc1 = MFMA16(a11, w1, acc1, 0,0,0); acc1 = MFMA16(a12, w0, acc1, 0,0,0);
      }
#pragma unroll
      for (int i = 0; i < 4; ++i){
        zp[wv][(kg * 4 + i) * 16 + r0]      = acc0[i];
        zp[wv][(16 + kg * 4 + i) * 16 + r0] = acc1[i];
      }
      __syncthreads();
      float z = 0.f;
#pragma unroll
      for (int w = 0; w < 8; ++w) z += zp[w][tid];
      z += a.bperm[colbase + (tid & 15)];
      __syncthreads();
      zp[0][tid] = z;
      __syncthreads();
      if (tid < 128){
        int b = tid >> 2, ul = tid & 3, u = blk * 4 + ul;
        float zi = zp[0][b * 16 + ul * 4 + 0];
        float zf = zp[0][b * 16 + ul * 4 + 1];
        float zg = zp[0][b * 16 + ul * 4 + 2];
        float zo = zp[0][b * 16 + ul * 4 + 3];
        float co = a.cbuf[b * 1024 + u];
        float cn = (1.f / (1.f + expf(-zf))) * co + (1.f / (1.f + expf(-zi))) * tanhf(zg);
        float hn = (1.f / (1.f + expf(-zo))) * tanhf(cn);
        a.cbuf[b * 1024 + u] = cn;
        a.hf32[b * 1024 + u] = hn;
        us16 s0, s1, s2; split3(hn, s0, s1, s2);
        a.hist[((size_t)(t + 1) * 32 + b) * 1536 + u] = s0;
        astore16(&a.hp[((size_t)(par * 3 + 0) * 32 + b) * 1024 + u], s0);
        astore16(&a.hp[((size_t)(par * 3 + 1) * 32 + b) * 1024 + u], s1);
        astore16(&a.hp[((size_t)(par * 3 + 2) * 32 + b) * 1024 + u], s2);
      }
    }
    gbar(a.bar, ++ep, tid, blk);

    // ===== phase B: q = h_new @ Wq (blocks 0..63, weights in regs); zero uctx =====
    if (blk < 64){
      f32x4 acc0 = (f32x4){0.f,0.f,0.f,0.f}, acc1 = acc0;
#pragma unroll
      for (int ks = 0; ks < 4; ++ks){
        const int kf = wv * 128 + ks * 32 + kg * 8;
        bf16x8 w0 = wq[ks][0], w1 = wq[ks][1], w2 = wq[ks][2];
        bf16x8 a00 = ld16(&a.hp[((size_t)(par * 3 + 0) * 32 + r0) * 1024 + kf]);
        bf16x8 a01 = ld16(&a.hp[((size_t)(par * 3 + 1) * 32 + r0) * 1024 + kf]);
        bf16x8 a02 = ld16(&a.hp[((size_t)(par * 3 + 2) * 32 + r0) * 1024 + kf]);
        bf16x8 a10 = ld16(&a.hp[((size_t)(par * 3 + 0) * 32 + r0 + 16) * 1024 + kf]);
        bf16x8 a11 = ld16(&a.hp[((size_t)(par * 3 + 1) * 32 + r0 + 16) * 1024 + kf]);
        bf16x8 a12 = ld16(&a.hp[((size_t)(par * 3 + 2) * 32 + r0 + 16) * 1024 + kf]);
        acc0 = MFMA16(a00, w0, acc0, 0,0,0); acc0 = MFMA16(a00, w1, acc0, 0,0,0);
        acc0 = MFMA16(a01, w0, acc0, 0,0,0); acc0 = MFMA16(a00, w2, acc0, 0,0,0);
        acc0 = MFMA16(a01, w1, acc0, 0,0,0); acc0 = MFMA16(a02, w0, acc0, 0,0,0);
        acc1 = MFMA16(a10, w0, acc1, 0,0,0); acc1 = MFMA16(a10, w1, acc1, 0,0,0);
        acc1 = MFMA16(a11, w0, acc1, 0,0,0); acc1 = MFMA16(a10, w2, acc1, 0,0,0);
        acc1 = MFMA16(a11, w1, acc1, 0,0,0); acc1 = MFMA16(a12, w0, acc1, 0,0,0);
      }
#pragma unroll
      for (int i = 0; i < 4; ++i){
        zp[wv][(kg * 4 + i) * 16 + r0]      = acc0[i];
        zp[wv][(16 + kg * 4 + i) * 16 + r0] = acc1[i];
      }
      __syncthreads();
      float q = 0.f;
#pragma unroll
      for (int w = 0; w < 8; ++w) q += zp[w][tid];
      astoref(&a.qbuf[(size_t)(tid >> 4) * 1024 + colbase + (tid & 15)], q);
    } else if (blk < 96){
      int i = (blk - 64) * 512 + tid;
      astoref(&a.uctx[par * 16384 + i], 0.f);
      if (blk == 64 && tid < 32) astoref(&a.sums[par * 32 + tid], 0.f);
    }
    gbar(a.bar, ++ep, tid, blk);

    // ===== phase C: score + exp + atomic ctx/sums (block = (b, s-slice32)) =====
    {
      float qv[16], vv[16];
      {
        const float* qp = a.qbuf + (size_t)cb_b * 1024 + u0;
        float4 q0 = *(const float4*)qp;
        float4 q1 = *(const float4*)(qp + 4);
        float4 q2 = *(const float4*)(qp + 8);
        float4 q3 = *(const float4*)(qp + 12);
        qv[0]=q0.x; qv[1]=q0.y; qv[2]=q0.z; qv[3]=q0.w;
        qv[4]=q1.x; qv[5]=q1.y; qv[6]=q1.z; qv[7]=q1.w;
        qv[8]=q2.x; qv[9]=q2.y; qv[10]=q2.z; qv[11]=q2.w;
        qv[12]=q3.x; qv[13]=q3.y; qv[14]=q3.z; qv[15]=q3.w;
        float4 v0 = *(const float4*)(a.vatt + u0);
        float4 v1 = *(const float4*)(a.vatt + u0 + 4);
        float4 v2 = *(const float4*)(a.vatt + u0 + 8);
        float4 v3 = *(const float4*)(a.vatt + u0 + 12);
        vv[0]=v0.x; vv[1]=v0.y; vv[2]=v0.z; vv[3]=v0.w;
        vv[4]=v1.x; vv[5]=v1.y; vv[6]=v1.z; vv[7]=v1.w;
        vv[8]=v2.x; vv[9]=v2.y; vv[10]=v2.z; vv[11]=v2.w;
        vv[12]=v3.x; vv[13]=v3.y; vv[14]=v3.z; vv[15]=v3.w;
      }
#pragma unroll
      for (int m = 0; m < 4; ++m){
        const int sl = wv * 4 + m;
        bf16x8 h0 = *(const bf16x8*)&khi[sl][u0];
        bf16x8 h1 = *(const bf16x8*)&khi[sl][u0 + 8];
        bf16x8 l0 = *(const bf16x8*)&klo[sl][u0];
        bf16x8 l1 = *(const bf16x8*)&klo[sl][u0 + 8];
        float part = 0.f;
#pragma unroll
        for (int j = 0; j < 8; ++j){
          float kva = h2f((us16)h0[j]) + h2f((us16)l0[j]);
          part += vv[j] * tanh_fast(kva + qv[j]);
          float kvb = h2f((us16)h1[j]) + h2f((us16)l1[j]);
          part += vv[8 + j] * tanh_fast(kvb + qv[8 + j]);
        }
#pragma unroll
        for (int off = 32; off; off >>= 1) part += __shfl_xor(part, off);
        if (lane == 0) esc[sl] = __expf(part);   // max-free softmax (|score| small)
      }
      __syncthreads();
      if (tid == 0){
        float bs = 0.f;
#pragma unroll
        for (int i = 0; i < 32; ++i) bs += esc[i];
        aaddf(&a.sums[par * 32 + cb_b], bs);
      }
      {
        float accv = 0.f;
        const float* mrow = a.mem + ((size_t)(cb_b * 256 + cb_s0)) * 512 + tid;
#pragma unroll 8
        for (int j = 0; j < 32; ++j) accv += esc[j] * mrow[(size_t)j * 512];
        aaddf(&a.uctx[par * 16384 + cb_b * 512 + tid], accv);
      }
    }
    gbar(a.bar, ++ep, tid, blk);
  }

  // epilogue: finalize hist[200] ctx part (final ctx lives in par=1 buffers)
  {
    if (tid < 32) rs_lds[tid] = 1.f / a.sums[32 + tid];
    __syncthreads();
    if (tid < 64){
      int flat = blk * 64 + tid;
      int b = flat >> 9, e = flat & 511;
      float v = a.uctx[16384 + flat];
      a.hist[(size_t)(200 * 32 + b) * 1536 + 1024 + e] = f2bf(v * rs_lds[b]);
    }
  }
}

__global__ void k_copy_hc(const float* __restrict__ h, const float* __restrict__ c,
                          float* __restrict__ out){
  int i = blockIdx.x * 256 + threadIdx.x;
  if (i < 32768){
    out[512000 + i] = h[i];
    out[544768 + i] = c[i];
  }
}

// ---------------------------------------------------------------------------
extern "C" void kernel_launch(void* const* d_in, const int* in_sizes, int n_in,
                              void* d_out, int out_size, void* d_ws, size_t ws_size,
                              hipStream_t stream){
  const float* inputs = (const float*)d_in[0];
  const float* memory = (const float*)d_in[1];
  const float* W1     = (const float*)d_in[2];
  const float* b1     = (const float*)d_in[3];
  const float* W2     = (const float*)d_in[4];
  const float* b2     = (const float*)d_in[5];
  const float* Wx     = (const float*)d_in[6];
  const float* Wh     = (const float*)d_in[7];
  const float* b_lstm = (const float*)d_in[8];
  const float* Wm     = (const float*)d_in[9];
  const float* Wq     = (const float*)d_in[10];
  const float* v_att  = (const float*)d_in[11];
  const float* Wa     = (const float*)d_in[12];
  const float* Wp     = (const float*)d_in[13];
  const float* bp     = (const float*)d_in[14];
  float* out = (float*)d_out;
  char* ws = (char*)d_ws;
  if (ws_size < TOTAL_WS) return;

  us16* WTA   = (us16*)(ws + OFF_WTA);
  us16* WQT   = (us16*)(ws + OFF_WQT);
  us16* X2P   = (us16*)(ws + OFF_X2P);
  us16* KEYH  = (us16*)(ws + OFF_KEYH);
  float* X1   = (float*)(ws + OFF_X1);
  us16* HIST  = (us16*)(ws + OFF_HIST);
  us16* HP    = (us16*)(ws + OFF_HP);
  float* QBUF = (float*)(ws + OFF_QBUF);
  float* UCTX = (float*)(ws + OFF_UCTX);
  float* SUMS = (float*)(ws + OFF_SUMS);
  float* CBUF = (float*)(ws + OFF_CBUF);
  float* HF32 = (float*)(ws + OFF_HF32);
  us16* WAPN  = (us16*)(ws + OFF_WAPN);
  float* BPM  = (float*)(ws + OFF_BPERM);
  u32*  BAR   = (u32*)(ws + OFF_BAR);

  k_zero_init<<<256, 256, 0, stream>>>((u32*)HP, (u32*)UCTX, (u32*)CBUF, SUMS, BAR);
  k_bperm<<<16, 256, 0, stream>>>(b_lstm, BPM);
  k_transp3<<<dim3(32, 32), 256, 0, stream>>>(Wq, WQT, 1024, 1024, 1024, (long long)WQPL, 0);
  k_transp3<<<dim3(128, 16), 256, 0, stream>>>(Wx, WTA, 512, 4096, 2048, (long long)WTPL, 1);

  // fold: WT_A[h|ctx rows] = Wa @ Wx_bot (+Wh on h rows), gate-permuted, triple-split
  k_gemm3<3,1,1><<<dim3(12, 64), 256, 0, stream>>>(Wa, Wx + (size_t)512 * 4096, WTA,
                                                   1536, 4096, 1024, 3, Wh, 0);
  // WapN = Wa @ Wp  [1536][80] bf16
  k_gemm3<3,1,1><<<dim3(12, 2), 256, 0, stream>>>(Wa, Wp, WAPN, 1536, 80, 1024, 4, nullptr, 80);
  // prenet 1: x1 = relu(inputs @ W1 + b1)  f32
  k_gemm3<3,1,1><<<dim3(50, 16), 256, 0, stream>>>(inputs, W1, X1, 6400, 1024, 80, 0, b1, 1024);
  // prenet 2: x2 = relu(x1 @ W2 + b2) -> triple planes
  k_gemm3<3,1,1><<<dim3(50, 8), 256, 0, stream>>>(X1, W2, X2P, 6400, 512, 1024, 1, b2, 512);
  // keys = memory @ Wm -> fp16 pair (overwrites X1 alias region)
  k_gemm3<3,1,1><<<dim3(64, 16), 256, 0, stream>>>(memory, Wm, KEYH, 8192, 1024, 512, 2, nullptr, 1024);

  CoopA ca;
  ca.wta = WTA; ca.wqt = WQT; ca.x2p = X2P; ca.kh = KEYH; ca.kl = KEYH + WTPL;
  ca.mem = memory; ca.vatt = v_att; ca.bperm = BPM;
  ca.hist = HIST; ca.hp = HP;
  ca.qbuf = QBUF; ca.uctx = UCTX; ca.sums = SUMS; ca.cbuf = CBUF; ca.hf32 = HF32;
  ca.bar = BAR;
  void* args[] = {(void*)&ca};
  hipLaunchCooperativeKernel((const void*)k_coop, dim3(256), dim3(512), args, 0, stream);

  // mel = hist[1..200] @ WapN + bp  (terminal precision: bf16 single)
  k_gemm3<1,0,0><<<dim3(50, 2), 256, 0, stream>>>(HIST + (size_t)32 * 1536, WAPN, out,
                                                  6400, 80, 1536, 5, bp, 0);
  // attn = hist[200] @ Wa
  k_gemm3<1,0,1><<<dim3(1, 16), 256, 0, stream>>>(HIST + (size_t)200 * 32 * 1536, Wa,
                                                  out + 577536, 32, 1024, 1536, 6, nullptr, 1024);
  k_copy_hc<<<128, 256, 0, stream>>>(HF32, CBUF, out);
}

// Round 8
// 12445.475 us; speedup vs baseline: 1.5804x; 1.5804x over previous
//
#include <hip/hip_runtime.h>

// ---------------------------------------------------------------------------
// TacotronMelDecoder on MI355X (gfx950) — precision-hardened persistent scan.
// R8: ROLLING per-step state buffers (h_roll / uctx_roll / qbuf_roll /
// sums_roll) with never-reused addresses. Cross-block state broadcast now
// goes through per-XCD L2 via plain cached loads with NO per-step fences —
// staleness is impossible because every address is written once (agent-scope
// write-through to MALL) and first cached-read only after the writing
// barrier. Replaces R5's ~60MB/step MALL-direct latency-bound gather.
// h stored fp32, triple-split in-register at consumers (bit-identical).
// 3 phases/step: A(ctx-finalize + z + gates) B(q) C(score + atomic ctx).
// ---------------------------------------------------------------------------

typedef unsigned short us16;
typedef unsigned int u32;
typedef unsigned long long u64;
typedef __attribute__((ext_vector_type(8))) short bf16x8;
typedef __attribute__((ext_vector_type(4))) float f32x4;

#define MFMA16 __builtin_amdgcn_mfma_f32_16x16x32_bf16
#define AGT __HIP_MEMORY_SCOPE_AGENT

__device__ __forceinline__ us16 f2bf(float f){
  u32 u = __builtin_bit_cast(u32, f);
  u += 0x7fffu + ((u >> 16) & 1u);
  return (us16)(u >> 16);
}
__device__ __forceinline__ float bf2f(us16 h){
  return __builtin_bit_cast(float, ((u32)h) << 16);
}
__device__ __forceinline__ float h2f(us16 u){
  _Float16 h = __builtin_bit_cast(_Float16, u); return (float)h;
}
__device__ __forceinline__ us16 f2h(float f){
  _Float16 h = (_Float16)f; return __builtin_bit_cast(us16, h);
}
__device__ __forceinline__ void split3(float v, us16& s0, us16& s1, us16& s2){
  s0 = f2bf(v); float r = v - bf2f(s0);
  s1 = f2bf(r); r -= bf2f(s1);
  s2 = f2bf(r);
}
__device__ __forceinline__ float tanh_fast(float x){
  float e = __expf(-2.f * fmaxf(x, -40.f));
  return (1.f - e) / (1.f + e);
}

__device__ __forceinline__ u32 aload32(const u32* p){
  return __hip_atomic_load(p, __ATOMIC_RELAXED, AGT);
}
__device__ __forceinline__ void astoref(float* p, float v){
  __hip_atomic_store(p, v, __ATOMIC_RELAXED, AGT);
}
__device__ __forceinline__ void aaddf(float* p, float v){
  __hip_atomic_fetch_add(p, v, __ATOMIC_RELAXED, AGT);
}
// opacity: force a loaded fragment to stay in VGPRs (non-rematerializable)
__device__ __forceinline__ bf16x8 pin_reg(bf16x8 v){
  f32x4 t = __builtin_bit_cast(f32x4, v);
  asm volatile("" : "+v"(t));
  return __builtin_bit_cast(bf16x8, t);
}
// 8 cached fp32 -> triple-split bf16 fragments (optionally scaled by rs)
__device__ __forceinline__ void f32_frag3(const float* p, float rs,
                                          bf16x8& f0, bf16x8& f1, bf16x8& f2){
  float4 t0 = *(const float4*)p;
  float4 t1 = *(const float4*)(p + 4);
  float tf[8] = {t0.x, t0.y, t0.z, t0.w, t1.x, t1.y, t1.z, t1.w};
#pragma unroll
  for (int i = 0; i < 8; ++i){
    float v = tf[i] * rs;
    us16 s0, s1, s2; split3(v, s0, s1, s2);
    f0[i] = (short)s0; f1[i] = (short)s1; f2[i] = (short)s2;
  }
}

// ---------------- workspace layout (bytes) ----------------
#define OFF_WTA    0ull            // 3 planes [4096][2048] bf16 (cols permuted u*4+gate)
#define OFF_WQT    50331648ull     // 3 planes [1024][1024] bf16 (Wq^T)
#define OFF_X2P    56623104ull     // 3 planes [32*200][512] bf16 (prenet out)
#define OFF_KEYH   76283904ull     // [8192][1024] fp16 hi
#define OFF_KEYL   93061120ull     // [8192][1024] fp16 lo
#define OFF_X1     76283904ull     // alias over KEYH/KEYL (dead before keys written)
#define OFF_HIST   109838336ull    // [201][32][1536] bf16 state history (epilogue only)
#define OFF_HROLL  129597440ull    // [201][32][1024] f32 h (rolling, write-once)
#define OFF_UCROLL 155942912ull    // [201][32][512] f32 raw ctx sums (rolling)
#define OFF_SROLL  169115648ull    // [201][32] f32 softmax sums (rolling; slot0=1)
#define OFF_QROLL  169141376ull    // [200][32][1024] f32 q (rolling)
#define OFF_CBUF   195355776ull    // [32][1024] f32 (block-private c state)
#define OFF_WAPN   195486848ull    // [1536][80] bf16 (Wa@Wp natural)
#define OFF_BPERM  195732608ull    // [4096] f32
#define OFF_BAR    195748992ull
#define TOTAL_WS   195750016ull

#define WTPL 8388608ull
#define WQPL 1048576ull
#define X2PL 3276800ull

// ---------------- init (re-run every launch: replay-safe) ----------------
__global__ void k_zero_init(float* hroll0, float* ucroll, float* sroll,
                            float* cbuf, u32* bar){
  u32 id = blockIdx.x * 256u + threadIdx.x;
  const u32 gs = 65536u;
  for (u32 i = id; i < 32768u;   i += gs) hroll0[i] = 0.f;
  for (u32 i = id; i < 3293184u; i += gs) ucroll[i] = 0.f;
  for (u32 i = id; i < 6432u;    i += gs) sroll[i]  = (i < 32u) ? 1.f : 0.f;
  for (u32 i = id; i < 32768u;   i += gs) cbuf[i]   = 0.f;
  for (u32 i = id; i < 256u;     i += gs) bar[i]    = 0u;
}

__global__ void k_bperm(const float* __restrict__ bl, float* __restrict__ bpm){
  int c = blockIdx.x * 256 + threadIdx.x;
  if (c < 4096) bpm[((c & 1023) << 2) | (c >> 10)] = bl[c];
}

// ---------------- transpose f32 -> 3 bf16 planes (+optional gate perm) ----------------
__global__ void k_transp3(const float* __restrict__ src, us16* __restrict__ dst,
                          int srows, int scols, int ldd, long long pstride, int perm){
  __shared__ float tile[32][33];
  int bx = blockIdx.x * 32, by = blockIdx.y * 32;
  int tx = threadIdx.x & 31, ty = threadIdx.x >> 5;
#pragma unroll
  for (int i = 0; i < 4; ++i){
    int r = by + ty + i * 8, c = bx + tx;
    tile[ty + i * 8][tx] = (r < srows && c < scols) ? src[(size_t)r * scols + c] : 0.f;
  }
  __syncthreads();
#pragma unroll
  for (int i = 0; i < 4; ++i){
    int c = bx + ty + i * 8;   // src col -> dst row
    int r = by + tx;           // src row -> dst col
    if (c < scols && r < srows){
      int oc = perm ? (((c & 1023) << 2) | (c >> 10)) : c;
      float v = tile[tx][ty + i * 8];
      us16 s0, s1, s2; split3(v, s0, s1, s2);
      size_t base = (size_t)oc * ldd + r;
      dst[base] = s0; dst[(size_t)pstride + base] = s1; dst[2ull * pstride + base] = s2;
    }
  }
}

// ---------------- generic triple-split GEMM: C[M,N] = A[M,K] @ B[K,N] ----------------
// modes: 0 f32+bias+relu | 1 relu -> x2 triple planes | 2 keys fp16 pair
//        3 fold -> WT_A triple planes (+Wh, gate perm) | 4 bf16 plain
//        5 mel f32 (+bias, row remap) | 6 f32 plain
template<int NP, int AF, int BF>
__global__ void __launch_bounds__(256)
k_gemm3(const void* __restrict__ Ap, const void* __restrict__ Bp, void* __restrict__ outp,
        int M, int N, int K, int mode, const float* __restrict__ aux, int ldd){
  __shared__ us16 At[NP][128][72];
  __shared__ us16 Bt[NP][64][72];
  const int tid = threadIdx.x, wv = tid >> 6, lane = tid & 63;
  const int r0 = lane & 15, kg = lane >> 4;
  const int rb = blockIdx.x * 128, cb = blockIdx.y * 64;
  f32x4 acc[2][4];
#pragma unroll
  for (int a = 0; a < 2; ++a)
#pragma unroll
    for (int b = 0; b < 4; ++b) acc[a][b] = (f32x4){0.f, 0.f, 0.f, 0.f};

  const int nkt = (K + 63) >> 6;
  for (int kt = 0; kt < nkt; ++kt){
    const int kb = kt * 64;
    for (int e = tid; e < 8192; e += 256){
      int r = e >> 6, k = e & 63, ga = rb + r, gk = kb + k;
      bool ok = (ga < M) && (gk < K);
      if constexpr (AF){
        float v = ok ? ((const float*)Ap)[(size_t)ga * K + gk] : 0.f;
        us16 s0, s1, s2; split3(v, s0, s1, s2);
        At[0][r][k] = s0;
        if constexpr (NP == 3){ At[1][r][k] = s1; At[2][r][k] = s2; }
      } else {
        At[0][r][k] = ok ? ((const us16*)Ap)[(size_t)ga * K + gk] : (us16)0;
      }
    }
    for (int e = tid; e < 4096; e += 256){
      int kr = e >> 6, c = e & 63, gk = kb + kr, gc = cb + c;
      bool ok = (gk < K) && (gc < N);
      if constexpr (BF){
        float v = ok ? ((const float*)Bp)[(size_t)gk * N + gc] : 0.f;
        us16 s0, s1, s2; split3(v, s0, s1, s2);
        Bt[0][c][kr] = s0;
        if constexpr (NP == 3){ Bt[1][c][kr] = s1; Bt[2][c][kr] = s2; }
      } else {
        Bt[0][c][kr] = ok ? ((const us16*)Bp)[(size_t)gk * N + gc] : (us16)0;
      }
    }
    __syncthreads();
#pragma unroll
    for (int kk = 0; kk < 64; kk += 32){
      bf16x8 af[NP][2];
#pragma unroll
      for (int p = 0; p < NP; ++p){
        af[p][0] = *(const bf16x8*)&At[p][wv * 32 + r0][kk + kg * 8];
        af[p][1] = *(const bf16x8*)&At[p][wv * 32 + 16 + r0][kk + kg * 8];
      }
#pragma unroll
      for (int cf = 0; cf < 4; ++cf){
        bf16x8 bv[NP];
#pragma unroll
        for (int p = 0; p < NP; ++p) bv[p] = *(const bf16x8*)&Bt[p][cf * 16 + r0][kk + kg * 8];
#pragma unroll
        for (int rf = 0; rf < 2; ++rf){
          acc[rf][cf] = MFMA16(af[0][rf], bv[0], acc[rf][cf], 0, 0, 0);
          if constexpr (NP == 3){
            acc[rf][cf] = MFMA16(af[0][rf], bv[1], acc[rf][cf], 0, 0, 0);
            acc[rf][cf] = MFMA16(af[1][rf], bv[0], acc[rf][cf], 0, 0, 0);
            acc[rf][cf] = MFMA16(af[0][rf], bv[2], acc[rf][cf], 0, 0, 0);
            acc[rf][cf] = MFMA16(af[1][rf], bv[1], acc[rf][cf], 0, 0, 0);
            acc[rf][cf] = MFMA16(af[2][rf], bv[0], acc[rf][cf], 0, 0, 0);
          }
        }
      }
    }
    __syncthreads();
  }
  us16* o16 = (us16*)outp; float* of = (float*)outp;
#pragma unroll
  for (int rf = 0; rf < 2; ++rf)
#pragma unroll
    for (int cf = 0; cf < 4; ++cf)
#pragma unroll
      for (int i = 0; i < 4; ++i){
        int r = rb + wv * 32 + rf * 16 + kg * 4 + i;
        int c = cb + cf * 16 + r0;
        if (r >= M || c >= N) continue;
        float v = acc[rf][cf][i];
        if (mode == 0){
          of[(size_t)r * ldd + c] = fmaxf(v + aux[c], 0.f);
        } else if (mode == 1){
          v = fmaxf(v + aux[c], 0.f);
          us16 s0, s1, s2; split3(v, s0, s1, s2);
          size_t b2 = (size_t)r * ldd + c;
          o16[b2] = s0; o16[X2PL + b2] = s1; o16[2 * X2PL + b2] = s2;
        } else if (mode == 2){
          us16 hh = f2h(v); float rem = v - h2f(hh); us16 hl = f2h(rem);
          size_t b2 = (size_t)r * 1024 + c;
          o16[b2] = hh; o16[WTPL + b2] = hl;
        } else if (mode == 3){
          float w = v + (r < 1024 ? aux[(size_t)r * 4096 + c] : 0.f);
          int pc = (c & 1023) * 4 + (c >> 10);
          us16 s0, s1, s2; split3(w, s0, s1, s2);
          size_t b2 = (size_t)pc * 2048 + 512 + r;
          o16[b2] = s0; o16[WTPL + b2] = s1; o16[2 * WTPL + b2] = s2;
        } else if (mode == 4){
          o16[(size_t)r * ldd + c] = f2bf(v);
        } else if (mode == 5){
          of[((size_t)(r & 31) * 200 + (r >> 5)) * 80 + c] = v + aux[c];
        } else {
          of[(size_t)r * ldd + c] = v;
        }
      }
}

// ---------------- global barrier (monotonic epoch, 8 groups of 32) ----------------
// NO per-step cache maintenance: rolling addresses make stale reads impossible.
__device__ __forceinline__ void gbar(u32* bar, u32 ep, int tid, int blk){
  __syncthreads();
  if (tid == 0){
    asm volatile("s_waitcnt vmcnt(0)" ::: "memory");
    u32 g = (u32)(blk >> 5);
    u32 old = __hip_atomic_fetch_add(&bar[g * 32], 1u, __ATOMIC_RELAXED, AGT);
    if (old == 32u * ep - 1u){
      u32 r = __hip_atomic_fetch_add(&bar[248], 1u, __ATOMIC_RELAXED, AGT);
      if (r == 8u * ep - 1u)
        __hip_atomic_store(&bar[252], ep, __ATOMIC_RELAXED, AGT);
    }
    while (aload32(&bar[252]) < ep) __builtin_amdgcn_s_sleep(1);
    __builtin_amdgcn_sched_barrier(0);
  }
  __syncthreads();
}

// ---------------- persistent scan kernel ----------------
struct CoopA {
  const us16 *wta, *wqt, *x2p, *kh, *kl;
  const float *mem, *vatt, *bperm;
  us16 *hist;
  float *hroll, *ucroll, *sroll, *qroll, *cbuf;
  u32 *bar;
};

__global__ void __launch_bounds__(512, 2) k_coop(CoopA a){
  __shared__ us16 khi[32][1024];
  __shared__ us16 klo[32][1024];
  __shared__ float zp[8][512];
  __shared__ float esc[32];
  __shared__ float rs_lds[32];

  // one-time invalidate: kill any stale L1/L2 lines from a previous launch
  __builtin_amdgcn_fence(__ATOMIC_ACQUIRE, "agent");

  const int tid = threadIdx.x, blk = blockIdx.x;
  const int wv = tid >> 6, lane = tid & 63;
  const int r0 = lane & 15, kg = lane >> 4;
  const int cb_b = blk >> 3, cb_s0 = (blk & 7) * 32;   // phase-C identity
  const int colbase = blk * 16;
  const int u0 = lane * 16;

  // WTA slice pinned in registers for all 200 steps (96 VGPRs/thread).
  bf16x8 wr[8][3];
#pragma unroll
  for (int ks = 0; ks < 8; ++ks){
    const size_t wb = (size_t)(colbase + r0) * 2048 + (size_t)wv * 256 + ks * 32 + kg * 8;
#pragma unroll
    for (int p = 0; p < 3; ++p)
      wr[ks][p] = pin_reg(*(const bf16x8*)&a.wta[(size_t)p * WTPL + wb]);
  }
  // WQT slice pinned for q-blocks (48 VGPRs on blocks 0..63)
  bf16x8 wq[4][3];
  if (blk < 64){
#pragma unroll
    for (int ks = 0; ks < 4; ++ks){
      const size_t wb = (size_t)(colbase + r0) * 1024 + (size_t)wv * 128 + ks * 32 + kg * 8;
#pragma unroll
      for (int p = 0; p < 3; ++p)
        wq[ks][p] = pin_reg(*(const bf16x8*)&a.wqt[(size_t)p * WQPL + wb]);
    }
  }

  // keys slice resident in LDS for all 200 steps
  {
    const size_t kbase = ((size_t)(cb_b * 256 + cb_s0)) * 1024;
    for (int i = tid; i < 4096; i += 512){
      int r = i >> 7, c8 = (i & 127) * 8;
      *(bf16x8*)&khi[r][c8] = *(const bf16x8*)&a.kh[kbase + (size_t)r * 1024 + c8];
      *(bf16x8*)&klo[r][c8] = *(const bf16x8*)&a.kl[kbase + (size_t)r * 1024 + c8];
    }
  }
  __syncthreads();

  u32 ep = 0;
  for (int t = 0; t < 200; ++t){
    // ===== phase A: ctx finalize inline; z = [x|h|ctx] @ WT_A (regs); gates =====
    {
      if (tid < 32) rs_lds[tid] = 1.f / a.sroll[(size_t)t * 32 + tid];
      __syncthreads();
      // side task: write hist[t] ctx part (state after step t-1) for epilogue
      if (tid < 64){
        int flat = blk * 64 + tid;          // 0..16383 = b*512+e
        int b = flat >> 9, e = flat & 511;
        float v = a.ucroll[(size_t)t * 16384 + flat];
        a.hist[(size_t)(t * 32 + b) * 1536 + 1024 + e] = f2bf(v * rs_lds[b]);
      }
      f32x4 acc0 = (f32x4){0.f,0.f,0.f,0.f}, acc1 = acc0;
#pragma unroll
      for (int ks = 0; ks < 8; ++ks){
        const int k0 = wv * 256 + ks * 32;
        const int kf = k0 + kg * 8;
        bf16x8 w0 = wr[ks][0], w1 = wr[ks][1], w2 = wr[ks][2];
        bf16x8 a00, a01, a02, a10, a11, a12;
        if (wv < 2){
          const size_t xb0 = ((size_t)r0 * 200 + t) * 512 + kf;
          const size_t xb1 = ((size_t)(r0 + 16) * 200 + t) * 512 + kf;
          a00 = *(const bf16x8*)&a.x2p[xb0];
          a01 = *(const bf16x8*)&a.x2p[X2PL + xb0];
          a02 = *(const bf16x8*)&a.x2p[2 * X2PL + xb0];
          a10 = *(const bf16x8*)&a.x2p[xb1];
          a11 = *(const bf16x8*)&a.x2p[X2PL + xb1];
          a12 = *(const bf16x8*)&a.x2p[2 * X2PL + xb1];
        } else if (wv < 6){
          const int hk = kf - 512;
          const float* hp0 = a.hroll + (size_t)t * 32768 + (size_t)r0 * 1024 + hk;
          f32_frag3(hp0,         1.f, a00, a01, a02);
          f32_frag3(hp0 + 16384, 1.f, a10, a11, a12);
        } else {
          const int ek = kf - 1536;
          const float* up = a.ucroll + (size_t)t * 16384 + (size_t)r0 * 512 + ek;
          f32_frag3(up,        rs_lds[r0],      a00, a01, a02);
          f32_frag3(up + 8192, rs_lds[r0 + 16], a10, a11, a12);
        }
        acc0 = MFMA16(a00, w0, acc0, 0,0,0); acc0 = MFMA16(a00, w1, acc0, 0,0,0);
        acc0 = MFMA16(a01, w0, acc0, 0,0,0); acc0 = MFMA16(a00, w2, acc0, 0,0,0);
        acc0 = MFMA16(a01, w1, acc0, 0,0,0); acc0 = MFMA16(a02, w0, acc0, 0,0,0);
        acc1 = MFMA16(a10, w0, acc1, 0,0,0); acc1 = MFMA16(a10, w1, acc1, 0,0,0);
        acc1 = MFMA16(a11, w0, acc1, 0,0,0); acc1 = MFMA16(a10, w2, acc1, 0,0,0);
        acc1 = MFMA16(a11, w1, acc1, 0,0,0); acc1 = MFMA16(a12, w0, acc1, 0,0,0);
      }
#pragma unroll
      for (int i = 0; i < 4; ++i){
        zp[wv][(kg * 4 + i) * 16 + r0]      = acc0[i];
        zp[wv][(16 + kg * 4 + i) * 16 + r0] = acc1[i];
      }
      __syncthreads();
      float z = 0.f;
#pragma unroll
      for (int w = 0; w < 8; ++w) z += zp[w][tid];
      z += a.bperm[colbase + (tid & 15)];
      __syncthreads();
      zp[0][tid] = z;
      __syncthreads();
      if (tid < 128){
        int b = tid >> 2, ul = tid & 3, u = blk * 4 + ul;
        float zi = zp[0][b * 16 + ul * 4 + 0];
        float zf = zp[0][b * 16 + ul * 4 + 1];
        float zg = zp[0][b * 16 + ul * 4 + 2];
        float zo = zp[0][b * 16 + ul * 4 + 3];
        float co = a.cbuf[b * 1024 + u];
        float cn = (1.f / (1.f + expf(-zf))) * co + (1.f / (1.f + expf(-zi))) * tanhf(zg);
        float hn = (1.f / (1.f + expf(-zo))) * tanhf(cn);
        a.cbuf[b * 1024 + u] = cn;                       // block-private
        astoref(&a.hroll[(size_t)(t + 1) * 32768 + b * 1024 + u], hn);
        us16 s0, s1, s2; split3(hn, s0, s1, s2);
        a.hist[((size_t)(t + 1) * 32 + b) * 1536 + u] = s0;
      }
    }
    gbar(a.bar, ++ep, tid, blk);

    // ===== phase B: q = h_new @ Wq (blocks 0..63, weights in regs) =====
    if (blk < 64){
      f32x4 acc0 = (f32x4){0.f,0.f,0.f,0.f}, acc1 = acc0;
#pragma unroll
      for (int ks = 0; ks < 4; ++ks){
        const int kf = wv * 128 + ks * 32 + kg * 8;
        bf16x8 w0 = wq[ks][0], w1 = wq[ks][1], w2 = wq[ks][2];
        bf16x8 a00, a01, a02, a10, a11, a12;
        const float* hp0 = a.hroll + (size_t)(t + 1) * 32768 + (size_t)r0 * 1024 + kf;
        f32_frag3(hp0,         1.f, a00, a01, a02);
        f32_frag3(hp0 + 16384, 1.f, a10, a11, a12);
        acc0 = MFMA16(a00, w0, acc0, 0,0,0); acc0 = MFMA16(a00, w1, acc0, 0,0,0);
        acc0 = MFMA16(a01, w0, acc0, 0,0,0); acc0 = MFMA16(a00, w2, acc0, 0,0,0);
        acc0 = MFMA16(a01, w1, acc0, 0,0,0); acc0 = MFMA16(a02, w0, acc0, 0,0,0);
        acc1 = MFMA16(a10, w0, acc1, 0,0,0); acc1 = MFMA16(a10, w1, acc1, 0,0,0);
        acc1 = MFMA16(a11, w0, acc1, 0,0,0); acc1 = MFMA16(a10, w2, acc1, 0,0,0);
        acc1 = MFMA16(a11, w1, acc1, 0,0,0); acc1 = MFMA16(a12, w0, acc1, 0,0,0);
      }
#pragma unroll
      for (int i = 0; i < 4; ++i){
        zp[wv][(kg * 4 + i) * 16 + r0]      = acc0[i];
        zp[wv][(16 + kg * 4 + i) * 16 + r0] = acc1[i];
      }
      __syncthreads();
      float q = 0.f;
#pragma unroll
      for (int w = 0; w < 8; ++w) q += zp[w][tid];
      astoref(&a.qroll[(size_t)t * 32768 + (size_t)(tid >> 4) * 1024 + colbase + (tid & 15)], q);
    }
    gbar(a.bar, ++ep, tid, blk);

    // ===== phase C: score + exp + atomic ctx/sums (block = (b, s-slice32)) =====
    {
      float qv[16], vv[16];
      {
        const float* qp = a.qroll + (size_t)t * 32768 + (size_t)cb_b * 1024 + u0;
        float4 q0 = *(const float4*)qp;
        float4 q1 = *(const float4*)(qp + 4);
        float4 q2 = *(const float4*)(qp + 8);
        float4 q3 = *(const float4*)(qp + 12);
        qv[0]=q0.x; qv[1]=q0.y; qv[2]=q0.z; qv[3]=q0.w;
        qv[4]=q1.x; qv[5]=q1.y; qv[6]=q1.z; qv[7]=q1.w;
        qv[8]=q2.x; qv[9]=q2.y; qv[10]=q2.z; qv[11]=q2.w;
        qv[12]=q3.x; qv[13]=q3.y; qv[14]=q3.z; qv[15]=q3.w;
        float4 v0 = *(const float4*)(a.vatt + u0);
        float4 v1 = *(const float4*)(a.vatt + u0 + 4);
        float4 v2 = *(const float4*)(a.vatt + u0 + 8);
        float4 v3 = *(const float4*)(a.vatt + u0 + 12);
        vv[0]=v0.x; vv[1]=v0.y; vv[2]=v0.z; vv[3]=v0.w;
        vv[4]=v1.x; vv[5]=v1.y; vv[6]=v1.z; vv[7]=v1.w;
        vv[8]=v2.x; vv[9]=v2.y; vv[10]=v2.z; vv[11]=v2.w;
        vv[12]=v3.x; vv[13]=v3.y; vv[14]=v3.z; vv[15]=v3.w;
      }
#pragma unroll
      for (int m = 0; m < 4; ++m){
        const int sl = wv * 4 + m;
        bf16x8 h0 = *(const bf16x8*)&khi[sl][u0];
        bf16x8 h1 = *(const bf16x8*)&khi[sl][u0 + 8];
        bf16x8 l0 = *(const bf16x8*)&klo[sl][u0];
        bf16x8 l1 = *(const bf16x8*)&klo[sl][u0 + 8];
        float part = 0.f;
#pragma unroll
        for (int j = 0; j < 8; ++j){
          float kva = h2f((us16)h0[j]) + h2f((us16)l0[j]);
          part += vv[j] * tanh_fast(kva + qv[j]);
          float kvb = h2f((us16)h1[j]) + h2f((us16)l1[j]);
          part += vv[8 + j] * tanh_fast(kvb + qv[8 + j]);
        }
#pragma unroll
        for (int off = 32; off; off >>= 1) part += __shfl_xor(part, off);
        if (lane == 0) esc[sl] = __expf(part);   // max-free softmax (|score| small)
      }
      __syncthreads();
      if (tid == 0){
        float bs = 0.f;
#pragma unroll
        for (int i = 0; i < 32; ++i) bs += esc[i];
        aaddf(&a.sroll[(size_t)(t + 1) * 32 + cb_b], bs);
      }
      {
        float ac0 = 0.f, ac1 = 0.f, ac2 = 0.f, ac3 = 0.f;
        const float* mrow = a.mem + ((size_t)(cb_b * 256 + cb_s0)) * 512 + tid;
#pragma unroll
        for (int j = 0; j < 32; j += 4){
          ac0 += esc[j]     * mrow[(size_t)j * 512];
          ac1 += esc[j + 1] * mrow[(size_t)(j + 1) * 512];
          ac2 += esc[j + 2] * mrow[(size_t)(j + 2) * 512];
          ac3 += esc[j + 3] * mrow[(size_t)(j + 3) * 512];
        }
        aaddf(&a.ucroll[(size_t)(t + 1) * 16384 + cb_b * 512 + tid], (ac0 + ac1) + (ac2 + ac3));
      }
    }
    gbar(a.bar, ++ep, tid, blk);
  }

  // epilogue: finalize hist[200] ctx part
  {
    if (tid < 32) rs_lds[tid] = 1.f / a.sroll[(size_t)200 * 32 + tid];
    __syncthreads();
    if (tid < 64){
      int flat = blk * 64 + tid;
      int b = flat >> 9, e = flat & 511;
      float v = a.ucroll[(size_t)200 * 16384 + flat];
      a.hist[(size_t)(200 * 32 + b) * 1536 + 1024 + e] = f2bf(v * rs_lds[b]);
    }
  }
}

__global__ void k_copy_hc(const float* __restrict__ h, const float* __restrict__ c,
                          float* __restrict__ out){
  int i = blockIdx.x * 256 + threadIdx.x;
  if (i < 32768){
    out[512000 + i] = h[i];
    out[544768 + i] = c[i];
  }
}

// ---------------------------------------------------------------------------
extern "C" void kernel_launch(void* const* d_in, const int* in_sizes, int n_in,
                              void* d_out, int out_size, void* d_ws, size_t ws_size,
                              hipStream_t stream){
  const float* inputs = (const float*)d_in[0];
  const float* memory = (const float*)d_in[1];
  const float* W1     = (const float*)d_in[2];
  const float* b1     = (const float*)d_in[3];
  const float* W2     = (const float*)d_in[4];
  const float* b2     = (const float*)d_in[5];
  const float* Wx     = (const float*)d_in[6];
  const float* Wh     = (const float*)d_in[7];
  const float* b_lstm = (const float*)d_in[8];
  const float* Wm     = (const float*)d_in[9];
  const float* Wq     = (const float*)d_in[10];
  const float* v_att  = (const float*)d_in[11];
  const float* Wa     = (const float*)d_in[12];
  const float* Wp     = (const float*)d_in[13];
  const float* bp     = (const float*)d_in[14];
  float* out = (float*)d_out;
  char* ws = (char*)d_ws;
  if (ws_size < TOTAL_WS) return;

  us16* WTA    = (us16*)(ws + OFF_WTA);
  us16* WQT    = (us16*)(ws + OFF_WQT);
  us16* X2P    = (us16*)(ws + OFF_X2P);
  us16* KEYH   = (us16*)(ws + OFF_KEYH);
  float* X1    = (float*)(ws + OFF_X1);
  us16* HIST   = (us16*)(ws + OFF_HIST);
  float* HROLL = (float*)(ws + OFF_HROLL);
  float* UCROLL= (float*)(ws + OFF_UCROLL);
  float* SROLL = (float*)(ws + OFF_SROLL);
  float* QROLL = (float*)(ws + OFF_QROLL);
  float* CBUF  = (float*)(ws + OFF_CBUF);
  us16* WAPN   = (us16*)(ws + OFF_WAPN);
  float* BPM   = (float*)(ws + OFF_BPERM);
  u32*  BAR    = (u32*)(ws + OFF_BAR);

  k_zero_init<<<256, 256, 0, stream>>>(HROLL, UCROLL, SROLL, CBUF, BAR);
  k_bperm<<<16, 256, 0, stream>>>(b_lstm, BPM);
  k_transp3<<<dim3(32, 32), 256, 0, stream>>>(Wq, WQT, 1024, 1024, 1024, (long long)WQPL, 0);
  k_transp3<<<dim3(128, 16), 256, 0, stream>>>(Wx, WTA, 512, 4096, 2048, (long long)WTPL, 1);

  // fold: WT_A[h|ctx rows] = Wa @ Wx_bot (+Wh on h rows), gate-permuted, triple-split
  k_gemm3<3,1,1><<<dim3(12, 64), 256, 0, stream>>>(Wa, Wx + (size_t)512 * 4096, WTA,
                                                   1536, 4096, 1024, 3, Wh, 0);
  // WapN = Wa @ Wp  [1536][80] bf16
  k_gemm3<3,1,1><<<dim3(12, 2), 256, 0, stream>>>(Wa, Wp, WAPN, 1536, 80, 1024, 4, nullptr, 80);
  // prenet 1: x1 = relu(inputs @ W1 + b1)  f32
  k_gemm3<3,1,1><<<dim3(50, 16), 256, 0, stream>>>(inputs, W1, X1, 6400, 1024, 80, 0, b1, 1024);
  // prenet 2: x2 = relu(x1 @ W2 + b2) -> triple planes
  k_gemm3<3,1,1><<<dim3(50, 8), 256, 0, stream>>>(X1, W2, X2P, 6400, 512, 1024, 1, b2, 512);
  // keys = memory @ Wm -> fp16 pair (overwrites X1 alias region)
  k_gemm3<3,1,1><<<dim3(64, 16), 256, 0, stream>>>(memory, Wm, KEYH, 8192, 1024, 512, 2, nullptr, 1024);

  CoopA ca;
  ca.wta = WTA; ca.wqt = WQT; ca.x2p = X2P; ca.kh = KEYH; ca.kl = KEYH + WTPL;
  ca.mem = memory; ca.vatt = v_att; ca.bperm = BPM;
  ca.hist = HIST; ca.hroll = HROLL; ca.ucroll = UCROLL; ca.sroll = SROLL;
  ca.qroll = QROLL; ca.cbuf = CBUF; ca.bar = BAR;
  void* args[] = {(void*)&ca};
  hipLaunchCooperativeKernel((const void*)k_coop, dim3(256), dim3(512), args, 0, stream);

  // mel = hist[1..200] @ WapN + bp  (terminal precision: bf16 single)
  k_gemm3<1,0,0><<<dim3(50, 2), 256, 0, stream>>>(HIST + (size_t)32 * 1536, WAPN, out,
                                                  6400, 80, 1536, 5, bp, 0);
  // attn = hist[200] @ Wa
  k_gemm3<1,0,1><<<dim3(1, 16), 256, 0, stream>>>(HIST + (size_t)200 * 32 * 1536, Wa,
                                                  out + 577536, 32, 1024, 1536, 6, nullptr, 1024);
  k_copy_hc<<<128, 256, 0, stream>>>(HROLL + (size_t)200 * 32768, CBUF, out);
}